// Round 1
// baseline (263.691 us; speedup 1.0000x reference)
//
#include <hip/hip_runtime.h>

// KernelRnn slow_update, fully fused single kernel. C=5 chemicals, R=14 rules,
// P = M*N = 2048*1024.
// h[p] = sum_c vy_c*chem[c][p]
//      + sum_c vz_c*tanh( sum_d K[c][d]*chem[d][p] )
//      + sum_r ( a_r*mean[r][p] + bi_r*var[r][p] - b_r*mean[r][p]^2 )
//
// R6 changes vs R5:
//  1. prep_kernel merged: each block computes the 83 coefficients into LDS
//     (first wave, Q/Ks/v/y/z are L2-resident after block 0). Removes one
//     graph node + the prep->fused dependency bubble.
//  2. Phase A processes rule pairs (r, r+1): 8 nontemporal loads in flight
//     per thread before the FMA block (was 4) -> fewer vmcnt stalls/byte.
//  3. Output stores are nontemporal (write-once, never re-read).
// Traffic is irreducible at 272 MiB (33 planes in + 1 out) -> ~43 us at
// 6.3 TB/s. R5's nt loads already removed the L1 set-thrash plateau.

#define CC 5
#define RR 14
#define VU 2   // float4 units per thread; tile = 256*VU*4 = 2048 floats

typedef float f32x4 __attribute__((ext_vector_type(4)));

__device__ __forceinline__ float fast_tanh(float x) {
    // tanh(x) = 1 - 2/(exp(2x)+1); argument here is tiny (|x| <~ 0.2)
    float e = __expf(2.0f * x);
    return fmaf(-2.0f, __builtin_amdgcn_rcpf(e + 1.0f), 1.0f);
}

__device__ __forceinline__ void fma4(f32x4& acc, float s, const f32x4& x) {
    acc.x = fmaf(s, x.x, acc.x);
    acc.y = fmaf(s, x.y, acc.y);
    acc.z = fmaf(s, x.z, acc.z);
    acc.w = fmaf(s, x.w, acc.w);
}

// LDS cf layout: [0..13]=a  [16..29]=bi  [32..45]=b  [48..52]=vy  [53..57]=vz  [58..82]=K
__global__ __launch_bounds__(256)
void fused_kernel(const float* __restrict__ chem,
                  const float* __restrict__ meanu,
                  const float* __restrict__ varu,
                  const float* __restrict__ Q,
                  const float* __restrict__ Ks,
                  const float* __restrict__ vv,
                  const float* __restrict__ yy,
                  const float* __restrict__ zz,
                  const int* __restrict__ tindex,
                  float* __restrict__ out,
                  int P) {
    __shared__ float cf[96];
    const int tid = threadIdx.x;

    // ---- per-block coefficient prep (was a separate kernel) ----
    if (tid < RR) {
        float inv_t = 1.0f / (float)tindex[0];
        float a = 0.0f, b = 0.0f;
        #pragma unroll
        for (int c = 0; c < CC; ++c) {
            float vz = vv[c] * zz[c];
            a = fmaf(vz, Q[c * (2 * RR) + tid], a);
            b = fmaf(vz, Q[c * (2 * RR) + RR + tid], b);
        }
        cf[tid] = a;
        cf[16 + tid] = b * inv_t;
        cf[32 + tid] = b;
    } else if (tid < RR + CC) {
        int c = tid - RR;
        cf[48 + c] = vv[c] * yy[c];
        cf[53 + c] = vv[c] * zz[c];
    } else if (tid < RR + CC + CC * CC) {
        int j = tid - (RR + CC);
        cf[58 + j] = Ks[j];
    }
    __syncthreads();

    const size_t tile = (size_t)blockIdx.x * (256 * VU * 4);  // in floats

    f32x4 acc[VU];
    #pragma unroll
    for (int u = 0; u < VU; ++u) acc[u] = (f32x4)(0.f);

    // ---- Phase A: rules, TWO (mean_r, var_r) plane pairs per iteration ----
    // 8 nontemporal loads issued back-to-back before the FMA block.
    #pragma unroll 1
    for (int r = 0; r < RR; r += 2) {
        const f32x4* pm0 = reinterpret_cast<const f32x4*>(meanu + (size_t)r * P + tile);
        const f32x4* pv0 = reinterpret_cast<const f32x4*>(varu  + (size_t)r * P + tile);
        const f32x4* pm1 = reinterpret_cast<const f32x4*>(meanu + (size_t)(r + 1) * P + tile);
        const f32x4* pv1 = reinterpret_cast<const f32x4*>(varu  + (size_t)(r + 1) * P + tile);
        f32x4 m0[VU], w0[VU], m1[VU], w1[VU];
        #pragma unroll
        for (int u = 0; u < VU; ++u) {
            m0[u] = __builtin_nontemporal_load(pm0 + u * 256 + tid);
            w0[u] = __builtin_nontemporal_load(pv0 + u * 256 + tid);
            m1[u] = __builtin_nontemporal_load(pm1 + u * 256 + tid);
            w1[u] = __builtin_nontemporal_load(pv1 + u * 256 + tid);
        }
        float a0 = cf[r],     bi0 = cf[16 + r],     b0 = cf[32 + r];
        float a1 = cf[r + 1], bi1 = cf[16 + r + 1], b1 = cf[32 + r + 1];
        #pragma unroll
        for (int u = 0; u < VU; ++u) {
            fma4(acc[u], a0, m0[u]);
            fma4(acc[u], bi0, w0[u]);
            f32x4 mm0 = m0[u] * m0[u];
            fma4(acc[u], -b0, mm0);
            fma4(acc[u], a1, m1[u]);
            fma4(acc[u], bi1, w1[u]);
            f32x4 mm1 = m1[u] * m1[u];
            fma4(acc[u], -b1, mm1);
        }
    }

    // ---- Phase B: chemicals (5 planes live — needed for tanh coupling) ----
    f32x4 ch[CC][VU];
    #pragma unroll
    for (int c = 0; c < CC; ++c) {
        const f32x4* pc = reinterpret_cast<const f32x4*>(chem + (size_t)c * P + tile);
        #pragma unroll
        for (int u = 0; u < VU; ++u) ch[c][u] = __builtin_nontemporal_load(pc + u * 256 + tid);
    }

    #pragma unroll
    for (int u = 0; u < VU; ++u) {
        // decay term: sum_c vy_c * chem_c
        #pragma unroll
        for (int c = 0; c < CC; ++c) {
            fma4(acc[u], cf[48 + c], ch[c][u]);
        }
        // mixing term: sum_c vz_c * tanh(K[c,:] . chem)
        #pragma unroll
        for (int c = 0; c < CC; ++c) {
            f32x4 s = (f32x4)(0.f);
            #pragma unroll
            for (int d = 0; d < CC; ++d) {
                fma4(s, cf[58 + c * CC + d], ch[d][u]);
            }
            float vz = cf[53 + c];
            acc[u].x = fmaf(vz, fast_tanh(s.x), acc[u].x);
            acc[u].y = fmaf(vz, fast_tanh(s.y), acc[u].y);
            acc[u].z = fmaf(vz, fast_tanh(s.z), acc[u].z);
            acc[u].w = fmaf(vz, fast_tanh(s.w), acc[u].w);
        }
    }

    f32x4* po = reinterpret_cast<f32x4*>(out + tile);
    #pragma unroll
    for (int u = 0; u < VU; ++u)
        __builtin_nontemporal_store(acc[u], po + u * 256 + tid);
}

extern "C" void kernel_launch(void* const* d_in, const int* in_sizes, int n_in,
                              void* d_out, int out_size, void* d_ws, size_t ws_size,
                              hipStream_t stream) {
    const float* chem  = (const float*)d_in[0];  // [C, M, N]
    const float* meanu = (const float*)d_in[1];  // [R, M, N]
    const float* varu  = (const float*)d_in[2];  // [R, M, N]
    const float* Q     = (const float*)d_in[3];  // [C, 2R]
    const float* Ks    = (const float*)d_in[4];  // [C, C]
    const float* v     = (const float*)d_in[5];  // [1, C]
    const float* y     = (const float*)d_in[6];  // [C]
    const float* z     = (const float*)d_in[7];  // [C]
    const int*   ti    = (const int*)d_in[8];    // scalar time_index

    float* out = (float*)d_out;  // [M, N] float32
    (void)d_ws; (void)ws_size;

    int P = out_size;                         // M*N = 2097152
    int tile_elems = 256 * VU * 4;            // 2048 floats per block
    int blocks = (P + tile_elems - 1) / tile_elems;
    fused_kernel<<<blocks, 256, 0, stream>>>(chem, meanu, varu, Q, Ks, v, y, z, ti, out, P);
}

// Round 2
// 262.214 us; speedup vs baseline: 1.0056x; 1.0056x over previous
//
#include <hip/hip_runtime.h>

// KernelRnn slow_update, fully fused single kernel. C=5 chemicals, R=14 rules,
// P = M*N = 2048*1024.
// h[p] = sum_c vy_c*chem[c][p]
//      + sum_c vz_c*tanh( sum_d K[c][d]*chem[d][p] )
//      + sum_r ( a_r*mean[r][p] + bi_r*var[r][p] - b_r*mean[r][p]^2 )
//
// R7 change vs R6 (single variable): the 10 chem-plane loads are issued
// FIRST (before Phase A). Per-wave loads retire in FIFO order, so by the
// time Phase B consumes them they have been in flight for the whole rule
// loop (~7 iterations of compute + 56 rule loads) -> the end-of-wave
// vmcnt wait on chem is free, removing the serial ~900-cycle HBM-latency
// tail that previously sat after Phase A in every wave.
// Traffic is irreducible at 272 MiB (33 planes in + 1 out) -> ~43 us at
// 6.3 TB/s achievable read BW.

#define CC 5
#define RR 14
#define VU 2   // float4 units per thread; tile = 256*VU*4 = 2048 floats

typedef float f32x4 __attribute__((ext_vector_type(4)));

__device__ __forceinline__ float fast_tanh(float x) {
    // tanh(x) = 1 - 2/(exp(2x)+1); argument here is tiny (|x| <~ 0.2)
    float e = __expf(2.0f * x);
    return fmaf(-2.0f, __builtin_amdgcn_rcpf(e + 1.0f), 1.0f);
}

__device__ __forceinline__ void fma4(f32x4& acc, float s, const f32x4& x) {
    acc.x = fmaf(s, x.x, acc.x);
    acc.y = fmaf(s, x.y, acc.y);
    acc.z = fmaf(s, x.z, acc.z);
    acc.w = fmaf(s, x.w, acc.w);
}

// LDS cf layout: [0..13]=a  [16..29]=bi  [32..45]=b  [48..52]=vy  [53..57]=vz  [58..82]=K
__global__ __launch_bounds__(256)
void fused_kernel(const float* __restrict__ chem,
                  const float* __restrict__ meanu,
                  const float* __restrict__ varu,
                  const float* __restrict__ Q,
                  const float* __restrict__ Ks,
                  const float* __restrict__ vv,
                  const float* __restrict__ yy,
                  const float* __restrict__ zz,
                  const int* __restrict__ tindex,
                  float* __restrict__ out,
                  int P) {
    __shared__ float cf[96];
    const int tid = threadIdx.x;
    const size_t tile = (size_t)blockIdx.x * (256 * VU * 4);  // in floats

    // ---- Prefetch: issue ALL chem loads first (consumed last, FIFO) ----
    f32x4 ch[CC][VU];
    #pragma unroll
    for (int c = 0; c < CC; ++c) {
        const f32x4* pc = reinterpret_cast<const f32x4*>(chem + (size_t)c * P + tile);
        #pragma unroll
        for (int u = 0; u < VU; ++u) ch[c][u] = __builtin_nontemporal_load(pc + u * 256 + tid);
    }

    // ---- per-block coefficient prep (overlaps with loads in flight) ----
    if (tid < RR) {
        float inv_t = 1.0f / (float)tindex[0];
        float a = 0.0f, b = 0.0f;
        #pragma unroll
        for (int c = 0; c < CC; ++c) {
            float vz = vv[c] * zz[c];
            a = fmaf(vz, Q[c * (2 * RR) + tid], a);
            b = fmaf(vz, Q[c * (2 * RR) + RR + tid], b);
        }
        cf[tid] = a;
        cf[16 + tid] = b * inv_t;
        cf[32 + tid] = b;
    } else if (tid < RR + CC) {
        int c = tid - RR;
        cf[48 + c] = vv[c] * yy[c];
        cf[53 + c] = vv[c] * zz[c];
    } else if (tid < RR + CC + CC * CC) {
        int j = tid - (RR + CC);
        cf[58 + j] = Ks[j];
    }
    __syncthreads();

    f32x4 acc[VU];
    #pragma unroll
    for (int u = 0; u < VU; ++u) acc[u] = (f32x4)(0.f);

    // ---- Phase A: rules, TWO (mean_r, var_r) plane pairs per iteration ----
    // 8 nontemporal loads issued back-to-back before the FMA block.
    #pragma unroll 1
    for (int r = 0; r < RR; r += 2) {
        const f32x4* pm0 = reinterpret_cast<const f32x4*>(meanu + (size_t)r * P + tile);
        const f32x4* pv0 = reinterpret_cast<const f32x4*>(varu  + (size_t)r * P + tile);
        const f32x4* pm1 = reinterpret_cast<const f32x4*>(meanu + (size_t)(r + 1) * P + tile);
        const f32x4* pv1 = reinterpret_cast<const f32x4*>(varu  + (size_t)(r + 1) * P + tile);
        f32x4 m0[VU], w0[VU], m1[VU], w1[VU];
        #pragma unroll
        for (int u = 0; u < VU; ++u) {
            m0[u] = __builtin_nontemporal_load(pm0 + u * 256 + tid);
            w0[u] = __builtin_nontemporal_load(pv0 + u * 256 + tid);
            m1[u] = __builtin_nontemporal_load(pm1 + u * 256 + tid);
            w1[u] = __builtin_nontemporal_load(pv1 + u * 256 + tid);
        }
        float a0 = cf[r],     bi0 = cf[16 + r],     b0 = cf[32 + r];
        float a1 = cf[r + 1], bi1 = cf[16 + r + 1], b1 = cf[32 + r + 1];
        #pragma unroll
        for (int u = 0; u < VU; ++u) {
            fma4(acc[u], a0, m0[u]);
            fma4(acc[u], bi0, w0[u]);
            f32x4 mm0 = m0[u] * m0[u];
            fma4(acc[u], -b0, mm0);
            fma4(acc[u], a1, m1[u]);
            fma4(acc[u], bi1, w1[u]);
            f32x4 mm1 = m1[u] * m1[u];
            fma4(acc[u], -b1, mm1);
        }
    }

    // ---- Phase B: chemicals (loads long since retired; vmcnt wait free) ----
    #pragma unroll
    for (int u = 0; u < VU; ++u) {
        // decay term: sum_c vy_c * chem_c
        #pragma unroll
        for (int c = 0; c < CC; ++c) {
            fma4(acc[u], cf[48 + c], ch[c][u]);
        }
        // mixing term: sum_c vz_c * tanh(K[c,:] . chem)
        #pragma unroll
        for (int c = 0; c < CC; ++c) {
            f32x4 s = (f32x4)(0.f);
            #pragma unroll
            for (int d = 0; d < CC; ++d) {
                fma4(s, cf[58 + c * CC + d], ch[d][u]);
            }
            float vz = cf[53 + c];
            acc[u].x = fmaf(vz, fast_tanh(s.x), acc[u].x);
            acc[u].y = fmaf(vz, fast_tanh(s.y), acc[u].y);
            acc[u].z = fmaf(vz, fast_tanh(s.z), acc[u].z);
            acc[u].w = fmaf(vz, fast_tanh(s.w), acc[u].w);
        }
    }

    f32x4* po = reinterpret_cast<f32x4*>(out + tile);
    #pragma unroll
    for (int u = 0; u < VU; ++u)
        __builtin_nontemporal_store(acc[u], po + u * 256 + tid);
}

extern "C" void kernel_launch(void* const* d_in, const int* in_sizes, int n_in,
                              void* d_out, int out_size, void* d_ws, size_t ws_size,
                              hipStream_t stream) {
    const float* chem  = (const float*)d_in[0];  // [C, M, N]
    const float* meanu = (const float*)d_in[1];  // [R, M, N]
    const float* varu  = (const float*)d_in[2];  // [R, M, N]
    const float* Q     = (const float*)d_in[3];  // [C, 2R]
    const float* Ks    = (const float*)d_in[4];  // [C, C]
    const float* v     = (const float*)d_in[5];  // [1, C]
    const float* y     = (const float*)d_in[6];  // [C]
    const float* z     = (const float*)d_in[7];  // [C]
    const int*   ti    = (const int*)d_in[8];    // scalar time_index

    float* out = (float*)d_out;  // [M, N] float32
    (void)d_ws; (void)ws_size;

    int P = out_size;                         // M*N = 2097152
    int tile_elems = 256 * VU * 4;            // 2048 floats per block
    int blocks = (P + tile_elems - 1) / tile_elems;
    fused_kernel<<<blocks, 256, 0, stream>>>(chem, meanu, varu, Q, Ks, v, y, z, ti, out, P);
}